// Round 10
// baseline (590.804 us; speedup 1.0000x reference)
//
#include <hip/hip_runtime.h>

#define V 16000
#define E 256
#define H 512
#define HP 516     // padded LDS h row stride (4-float pad: bank groups 4r)
#define BB 8       // batch rows
#define T 12       // lenseq
#define NB 250     // persistent blocks: 250*64 == 16000 exactly (1 block/CU)
#define NBS 256    // pq stride (padded)
#define TPB 1024   // 16 waves/block
#define CPB 64     // vocab cols per block: 64*4B = 256B row slice, LINE-ALIGNED
#define BBH (BB * H)
#define AGENT __HIP_MEMORY_SCOPE_AGENT

typedef float vfloat4 __attribute__((ext_vector_type(4)));
typedef unsigned long long u64;

// Greedy degeneracy verified (R3). Persistent kernel since R4. w_out in LDS
// since R9. Established: (i) WRITE_SIZE amplification is a red herring
// (pattern/NT-invariant, uncorrelated with dur). (ii) Cross-block traffic
// via cache-bypassing relaxed atomics; R14 tree barrier is the proven sync
// structure (R15 flat -65us, R16 fused+acquire -690us, R17 plain-stores
// -30us). R18 op-shaping (+12us win): coalesced 8B h stores, packed pq,
// producer-only bar1. R19 (this round): attack the ~25us/step unexplained
// sync latency = hot-line poll contention. (1) EPOCH RELAY: block0 publishes
// each epoch to 8 read-only relay lines; block b polls line b&7 with
// s_sleep(4) -> ~31 pollers/line at 1/4 rate, no L3 bank queue. (2) TAGGED
// CACHED pq: 16B {sum,max,idx,tag} records; writer 8B relaxed + 8B RELEASE
// bypass; reader ONE plain cached vfloat4 + tag check (bypass fallback on
// stale). L2 amortizes the 250-reader fan-out; dispatch-unique tag (kinit
// clock-salted counter, graph-replay-safe) makes staleness detectable by
// construction. h exchange unchanged (bypass).

// LDS layout (floats)
constexpr int W_FL   = CPB * 512;            // 32768  swizzled w slice (128KB)
constexpr int SH_OFF = W_FL;                 // s_h   [8][516]
constexpr int SP_OFF = SH_OFF + BB * HP;     // s_part 64*48 (A) / s_e [8][65] (B/C)
constexpr int RS_OFF = SP_OFF + 64 * 48;     // s_rsum [16][8] (+ phase-A h gather)
constexpr int RV_OFF = RS_OFF + 128;         // s_rval
constexpr int RI_OFF = RV_OFF + 128;         // s_ridx (int)
constexpr int SS_OFF = RI_OFF + 128;         // s_S   [8]
constexpr int XN_OFF = SS_OFF + 8;           // s_Xn  [8] (int)
constexpr int X_OFF  = XN_OFF + 8;           // s_X   [8] (int)
constexpr int DC_OFF = X_OFF + 8;            // s_dct [1] (int)
constexpr int SMEM_FL = DC_OFF + 1;
constexpr size_t SMEM_BYTES = (size_t)SMEM_FL * 4;   // 161,508 B < 160 KiB

// cnt line map (16 ints per line):
//   lines 0..62 : bar2 leaf counters (62x4 + 2 = 250 arrivals)
//   lines 64..79: bar1 leaf counters (16 x 4 = 64 producer arrivals)
//   lines 84..91: epochA relay lines (block0 writes, block b polls 84+(b&7))
//   lines 92..99: epochB relay lines
constexpr int CNT_LINES = 100;

__device__ __forceinline__ float dot4(float4 a, float4 b) {
    return a.x * b.x + a.y * b.y + a.z * b.z + a.w * b.w;
}

__global__ __launch_bounds__(256) void kinit(const float* __restrict__ hidden,
                                             float* __restrict__ hbuf,
                                             int* __restrict__ cnt,
                                             int* __restrict__ dct) {
    int idx = blockIdx.x * 256 + threadIdx.x;
    if (idx < BBH) hbuf[idx] = hidden[idx];
    if (idx < CNT_LINES * 16) cnt[idx] = 0;
    if (blockIdx.x == 0 && threadIdx.x == 0) {
        // dispatch-unique tag salt: monotonic + clock entropy. Runs inside
        // the dispatch -> graph-replay-safe.
        int old = __hip_atomic_load(dct, __ATOMIC_RELAXED, AGENT);
        int tk  = (int)(__builtin_amdgcn_s_memtime() >> 6);
        __hip_atomic_store(dct, old + ((tk | 1) & 0xFFFF),
                           __ATOMIC_RELAXED, AGENT);
    }
}

// bar1: producer-only arrivals (blocks 0..63 on 16 leaf lines) -> block0
// detects, publishes epoch to 8 relay lines -> block b polls line b&7.
__device__ __forceinline__ void barA(int* __restrict__ cnt, int ep) {
    __syncthreads();
    if (blockIdx.x < 64 && threadIdx.x == 0)
        __hip_atomic_fetch_add(&cnt[(64 + (blockIdx.x >> 2)) * 16], 1,
                               __ATOMIC_RELEASE, AGENT);
    if (blockIdx.x == 0) {
        if (threadIdx.x < 16) {
            while (__hip_atomic_load(&cnt[(64 + threadIdx.x) * 16],
                                     __ATOMIC_RELAXED, AGENT) < 4 * ep)
                __builtin_amdgcn_s_sleep(1);
        }
        __syncthreads();
        if (threadIdx.x < 8)
            __hip_atomic_store(&cnt[(84 + threadIdx.x) * 16], ep,
                               __ATOMIC_RELAXED, AGENT);
    } else {
        if (threadIdx.x == 0) {
            while (__hip_atomic_load(&cnt[(84 + (blockIdx.x & 7)) * 16],
                                     __ATOMIC_RELAXED, AGENT) < ep)
                __builtin_amdgcn_s_sleep(4);
        }
    }
    __builtin_amdgcn_fence(__ATOMIC_ACQUIRE, "workgroup");
    __syncthreads();
}

// bar2: full-grid tree (63 leaves; leaf 62 has 2 blocks) + 8-line relay.
__device__ __forceinline__ void barB(int* __restrict__ cnt, int ep) {
    __syncthreads();
    if (threadIdx.x == 0) {
        int g = blockIdx.x >> 2;
        __hip_atomic_fetch_add(&cnt[g * 16], 1, __ATOMIC_RELEASE, AGENT);
    }
    if (blockIdx.x == 0) {
        if (threadIdx.x < 63) {
            int expct = (threadIdx.x == 62) ? 2 : 4;   // 62*4 + 2 = 250
            while (__hip_atomic_load(&cnt[threadIdx.x * 16],
                                     __ATOMIC_RELAXED, AGENT) < expct * ep)
                __builtin_amdgcn_s_sleep(1);
        }
        __syncthreads();
        if (threadIdx.x < 8)
            __hip_atomic_store(&cnt[(92 + threadIdx.x) * 16], ep,
                               __ATOMIC_RELAXED, AGENT);
    } else {
        if (threadIdx.x == 0) {
            while (__hip_atomic_load(&cnt[(92 + (blockIdx.x & 7)) * 16],
                                     __ATOMIC_RELAXED, AGENT) < ep)
                __builtin_amdgcn_s_sleep(4);
        }
    }
    __builtin_amdgcn_fence(__ATOMIC_ACQUIRE, "workgroup");
    __syncthreads();
}

__global__ __launch_bounds__(TPB, 4) void kmain(
    const float* __restrict__ emb_tab,
    const float* __restrict__ w_ih,
    const float* __restrict__ w_hh,
    const float* __restrict__ b_ih,
    const float* __restrict__ b_hh,
    const float* __restrict__ w_out,
    const float* __restrict__ b_out,
    float* __restrict__ hbuf,   // [T+1][BB*H] rotated h buffers
    vfloat4* __restrict__ pq,   // [T][8][NBS] {sum,max,idxbits,tagbits}
    int* __restrict__ cnt,
    int* __restrict__ dct,
    float* __restrict__ out)
{
    extern __shared__ float smem[];
    float* w_lds  = smem;
    float* s_h    = smem + SH_OFF;
    float* s_part = smem + SP_OFF;
    float* s_e    = smem + SP_OFF;          // alias: phase-B/C e buffer [8][65]
    float* s_rsum = smem + RS_OFF;
    float* s_rval = smem + RV_OFF;
    int*   s_ridx = (int*)(smem + RI_OFF);
    float* s_S    = smem + SS_OFF;
    int*   s_Xn   = (int*)(smem + XN_OFF);
    int*   s_X    = (int*)(smem + X_OFF);
    int*   s_dct  = (int*)(smem + DC_OFF);

    const int blk = blockIdx.x, tid = threadIdx.x;

    // ---- stage this block's w_out slice into LDS, swizzled, ONCE ----------
    // layout: w_lds[col*512 + (k ^ ((col&7)<<2) ^ (((k>>5)&7)<<2))]
    for (int i = tid; i < CPB * 128; i += TPB) {
        int col = i >> 7;
        int q4  = (i & 127) << 2;
        int vv  = blk * CPB + col;          // always < V (250*64 == 16000)
        float4 w4 = *(const float4*)(w_out + (size_t)vv * H + q4);
        int sw = q4 ^ ((col & 7) << 2) ^ (((q4 >> 5) & 7) << 2);
        *(float4*)(w_lds + col * 512 + sw) = w4;
    }
    if (tid < BB) s_X[tid] = 1;             // SOS
    if (tid == 0)
        *s_dct = __hip_atomic_load(dct, __ATOMIC_RELAXED, AGENT);
    __syncthreads();
    const int tagbase = (*s_dct) << 4;      // tag = tagbase | (t+1)

    // ---- phase-B lane mapping: rh=bits0-1, kq=bits2-5 (16 K-chunks of 32)
    // wave: rowhalf=bit0, col-slot cs=bits1-4; per pass p: col = p*8 + cs
    const int lane = tid & 63;
    const int wv   = tid >> 6;              // 0..15
    const int rh   = lane & 3;
    const int kq   = (lane >> 2) & 15;      // K chunk (32 floats)
    const int rowhalf = wv & 1;
    const int cs   = wv >> 1;               // 0..7
    const int r    = rowhalf * 4 + rh;      // 0..7
    const int xw   = (cs ^ (kq & 7)) << 2;  // w swizzle for this (col-slot,kq)
    const int hswz = (kq & 7) << 2;         // h swizzle for this kq

    // b_out is step-invariant: hoist the 8 per-pass values into VGPRs once
    float bo[8];
#pragma unroll
    for (int p = 0; p < 8; p++) bo[p] = b_out[blk * CPB + p * 8 + cs];

    for (int t = 0; t < T; t++) {
        const float* h_cur = hbuf + (size_t)t * BBH;        // rotated
        float*       h_nxt = hbuf + (size_t)(t + 1) * BBH;  // write-once
        const int tagv = tagbase | (t + 1);

        // ---------------- phase A: GRU cell (blocks 0..63) ----------------
        if (blk < 64) {                     // stage h_cur (8B bypass loads)
            int hr = tid >> 7, k4 = (tid & 127) << 2;
            const u64* p = (const u64*)(h_cur + hr * H + k4);
            union { u64 u; float f[2]; } c0, c1;
            c0.u = __hip_atomic_load(p,     __ATOMIC_RELAXED, AGENT);
            c1.u = __hip_atomic_load(p + 1, __ATOMIC_RELAXED, AGENT);
            *(float4*)(s_h + hr * HP + k4) =
                make_float4(c0.f[0], c0.f[1], c1.f[0], c1.f[1]);
        }
        __syncthreads();
        if (blk < 64 && tid < 512) {
            const int jl = tid >> 6;        // 0..7
            const int ar = (tid >> 3) & 7;  // row
            const int kq8 = tid & 7;        // K split 8
            const int j  = blk * 8 + jl;
            const int pair = jl * 8 + ar;
            float gir = 0.f, giz = 0.f, gin = 0.f, ghr = 0.f, ghz = 0.f, ghn = 0.f;
            {
                const float* erow = emb_tab + (size_t)s_X[ar] * E;
                const float* w0 = w_ih + (size_t)j * E;
                const float* w1 = w0 + (size_t)H * E;
                const float* w2 = w1 + (size_t)H * E;
                const int k0 = kq8 * (E / 8);
                for (int k = 0; k < E / 8; k += 4) {
                    float4 ev = *(const float4*)(erow + k0 + k);
                    gir += dot4(*(const float4*)(w0 + k0 + k), ev);
                    giz += dot4(*(const float4*)(w1 + k0 + k), ev);
                    gin += dot4(*(const float4*)(w2 + k0 + k), ev);
                }
            }
            {
                const float* hrow = s_h + ar * HP;
                const float* w0 = w_hh + (size_t)j * H;
                const float* w1 = w0 + (size_t)H * H;
                const float* w2 = w1 + (size_t)H * H;
                const int k0 = kq8 * (H / 8);
                for (int k = 0; k < H / 8; k += 4) {
                    float4 hv = *(const float4*)(hrow + k0 + k);
                    ghr += dot4(*(const float4*)(w0 + k0 + k), hv);
                    ghz += dot4(*(const float4*)(w1 + k0 + k), hv);
                    ghn += dot4(*(const float4*)(w2 + k0 + k), hv);
                }
            }
            float* sp = s_part + pair * 48;
            sp[0 * 8 + kq8] = gir; sp[1 * 8 + kq8] = giz; sp[2 * 8 + kq8] = gin;
            sp[3 * 8 + kq8] = ghr; sp[4 * 8 + kq8] = ghz; sp[5 * 8 + kq8] = ghn;
        }
        __syncthreads();
        if (blk < 64 && tid < 512 && (tid & 7) == 0) {
            const int pair = (tid >> 6) * 8 + ((tid >> 3) & 7);
            const int jl = pair >> 3, ar = pair & 7;
            const int j  = blk * 8 + jl;
            const float* sp2 = s_part + pair * 48;
            float G[6];
#pragma unroll
            for (int gg = 0; gg < 6; gg++) {
                float s = 0.f;
#pragma unroll
                for (int q = 0; q < 8; q++) s += sp2[gg * 8 + q];
                G[gg] = s;
            }
            float ir  = G[0] + b_ih[j],         hr_ = G[3] + b_hh[j];
            float iz  = G[1] + b_ih[H + j],     hz  = G[4] + b_hh[H + j];
            float inn = G[2] + b_ih[2 * H + j], hn  = G[5] + b_hh[2 * H + j];
            float rg = 1.f / (1.f + __expf(-(ir + hr_)));
            float zg = 1.f / (1.f + __expf(-(iz + hz)));
            float ng = tanhf(inn + rg * hn);
            float ho = s_h[ar * HP + j];
            int xr = s_X[ar];
            bool dn = (xr == 0) || (xr == 2);
            float hv = dn ? ho : ((1.f - zg) * ng + zg * ho);
            s_rsum[ar * 8 + jl] = hv;       // gather for packed store
        }
        __syncthreads();
        if (blk < 64 && tid < 32) {         // 32 coalesced 8B bypass stores
            int ar = tid >> 2, q2 = (tid & 3) << 1;
            union { float f[2]; u64 u; } pk;
            pk.f[0] = s_rsum[ar * 8 + q2];
            pk.f[1] = s_rsum[ar * 8 + q2 + 1];
            __hip_atomic_store((u64*)(h_nxt + (size_t)ar * H + blk * 8 + q2),
                               pk.u, __ATOMIC_RELAXED, AGENT);
        }
        barA(cnt, t + 1);

        // -------- phase B: logits from LDS-resident w ----------------------
        {   // stage h_nxt, kq-swizzled (8B bypass loads)
            int hr = tid >> 7, k4 = (tid & 127) << 2;
            const u64* p = (const u64*)(h_nxt + hr * H + k4);
            union { u64 u; float f[2]; } c0, c1;
            c0.u = __hip_atomic_load(p,     __ATOMIC_RELAXED, AGENT);
            c1.u = __hip_atomic_load(p + 1, __ATOMIC_RELAXED, AGENT);
            int sw = k4 ^ (((k4 >> 5) & 7) << 2);
            *(float4*)(s_h + hr * HP + sw) =
                make_float4(c0.f[0], c0.f[1], c1.f[0], c1.f[1]);
        }
        __syncthreads();
        {
            // h chunk -> 32 VGPRs, read ONCE per step
            float4 hreg[8];
            const float* hb = s_h + r * HP + kq * 32;
#pragma unroll
            for (int i = 0; i < 8; i++)
                hreg[i] = *(const float4*)(hb + ((4 * i) ^ hswz));

            float s_acc = 0.f, bv = -1.f; int bi = 0x7fffffff;
#pragma unroll
            for (int p = 0; p < 8; p++) {
                const int col = p * 8 + cs;
                const int vv  = blk * CPB + col;
                const float* wb = w_lds + col * 512 + kq * 32;
                float acc = 0.f;
#pragma unroll
                for (int i = 0; i < 8; i++) {
                    float4 w4 = *(const float4*)(wb + ((4 * i) ^ xw));
                    acc += dot4(w4, hreg[i]);
                }
                // full-K sum across the 16 kq lanes (bits 2-5); butterfly is
                // commutative-add -> bitwise identical on every lane
                acc += __shfl_xor(acc, 4, 64);
                acc += __shfl_xor(acc, 8, 64);
                acc += __shfl_xor(acc, 16, 64);
                acc += __shfl_xor(acc, 32, 64);
                float ee = __expf(acc + bo[p]);
                if (kq == 0) s_e[r * 65 + col] = ee;  // stash for phase-C write
                s_acc += ee;
                if (ee > bv) { bv = ee; bi = vv; }  // earlier pass = smaller v
            }
            if (kq == 0) {                  // designated: real per-r results
                s_rsum[wv * 8 + r] = s_acc;
                s_rval[wv * 8 + r] = bv;
                s_ridx[wv * 8 + r] = bi;
            } else if (kq == 1) {           // neutral fill for other row-half
                int ro = (1 - rowhalf) * 4 + rh;
                s_rsum[wv * 8 + ro] = 0.f;
                s_rval[wv * 8 + ro] = -1.f;
                s_ridx[wv * 8 + ro] = 0x7fffffff;
            }
        }
        __syncthreads();
        if (tid < 64) {                     // reduce 16 waves -> per-row, store
            float s  = s_rsum[tid] + s_rsum[tid + 64];
            float av = s_rval[tid], bv2 = s_rval[tid + 64];
            int   ai = s_ridx[tid], bi2 = s_ridx[tid + 64];
            float bv = av; int bi = ai;
            if (bv2 > bv || (bv2 == bv && bi2 < bi)) { bv = bv2; bi = bi2; }
#pragma unroll
            for (int m = 8; m <= 32; m <<= 1) {
                s += __shfl_xor(s, m, 64);
                float ov = __shfl_xor(bv, m, 64);
                int   oi = __shfl_xor(bi, m, 64);
                if (ov > bv || (ov == bv && oi < bi)) { bv = ov; bi = oi; }
            }
            if (tid < 8) {                  // 16B tagged record, 2x8B bypass;
                u64* pp = (u64*)(pq + (size_t)(t * 8 + tid) * NBS + blk);
                union { float f[2]; u64 u; } lo;
                lo.f[0] = s; lo.f[1] = bv;
                __hip_atomic_store(pp, lo.u, __ATOMIC_RELAXED, AGENT);
                u64 hi = (u64)(unsigned)bi | ((u64)(unsigned)tagv << 32);
                // RELEASE orders the {sum,max} half before the tagged half.
                __hip_atomic_store(pp + 1, hi, __ATOMIC_RELEASE, AGENT);
            }
        }
        barB(cnt, t + 1);

        // ------- phase C: redundant reduce (cached tagged loads) -----------
        if (wv < 8) {
            const vfloat4* pqt = pq + (size_t)(t * 8 + wv) * NBS;
            float s = 0.f, bv = -1.f; int bi = 0x7fffffff;
#pragma unroll
            for (int c = 0; c < 4; c++) {
                int idx = lane + 64 * c;
                if (idx < NB) {
                    vfloat4 q = pqt[idx];   // plain cached load (one line)
                    float qs, qv; int qi;
                    if (__float_as_uint(q.w) == (unsigned)tagv) {
                        qs = q.x; qv = q.y;
                        qi = (int)__float_as_uint(q.z);
                    } else {                // stale L2 line: bypass reload
                        const u64* pp = (const u64*)(pqt + idx);
                        union { u64 u; float f[2]; } lo;
                        lo.u = __hip_atomic_load(pp, __ATOMIC_RELAXED, AGENT);
                        u64 hi = __hip_atomic_load(pp + 1,
                                                   __ATOMIC_RELAXED, AGENT);
                        qs = lo.f[0]; qv = lo.f[1];
                        qi = (int)(unsigned)(hi & 0xFFFFFFFFu);
                    }
                    s += qs;
                    if (qv > bv || (qv == bv && qi < bi)) { bv = qv; bi = qi; }
                }
            }
            for (int m = 1; m < 64; m <<= 1) {
                s += __shfl_xor(s, m, 64);
                float ov = __shfl_xor(bv, m, 64);
                int   oi = __shfl_xor(bi, m, 64);
                if (ov > bv || (ov == bv && oi < bi)) { bv = ov; bi = oi; }
            }
            if (lane == 0) { s_S[wv] = s; s_Xn[wv] = bi; }
        }
        __syncthreads();
        {   // out write: FULL-LINE NT vfloat4 stores. Row slice = 256B aligned.
            float* out_t = out + (size_t)t * BB * V;
            if (tid < 128) {
                int row = tid >> 4;         // 0..7
                int c4  = (tid & 15) << 2;  // 0,4,...,60
                int xr = s_X[row];
                bool dn = (xr == 0) || (xr == 2);
                float inv = 1.f / s_S[row];
                int vbase = blk * CPB + c4;
                vfloat4 o4;
                o4.x = dn ? ((vbase + 0 == 0) ? 1.f : 0.f) : s_e[row * 65 + c4 + 0] * inv;
                o4.y = dn ? ((vbase + 1 == 0) ? 1.f : 0.f) : s_e[row * 65 + c4 + 1] * inv;
                o4.z = dn ? ((vbase + 2 == 0) ? 1.f : 0.f) : s_e[row * 65 + c4 + 2] * inv;
                o4.w = dn ? ((vbase + 3 == 0) ? 1.f : 0.f) : s_e[row * 65 + c4 + 3] * inv;
                __builtin_nontemporal_store(o4,
                    (vfloat4*)(out_t + (size_t)row * V + vbase));
            }
        }
        __syncthreads();
        if (tid < 8) {
            int xo = s_X[tid];
            s_X[tid] = ((xo == 0) || (xo == 2)) ? 0 : s_Xn[tid];
        }
        __syncthreads();
    }
}

extern "C" void kernel_launch(void* const* d_in, const int* in_sizes, int n_in,
                              void* d_out, int out_size, void* d_ws, size_t ws_size,
                              hipStream_t stream) {
    (void)in_sizes; (void)n_in; (void)out_size; (void)ws_size;
    const float* hidden    = (const float*)d_in[0];
    const float* embedding = (const float*)d_in[1];
    const float* w_ih      = (const float*)d_in[2];
    const float* w_hh      = (const float*)d_in[3];
    const float* b_ih      = (const float*)d_in[4];
    const float* b_hh      = (const float*)d_in[5];
    const float* w_out     = (const float*)d_in[6];
    const float* b_out     = (const float*)d_in[7];
    float* out = (float*)d_out;

    float* ws      = (float*)d_ws;
    float* hbuf    = ws;                             // (T+1)*BBH floats
    vfloat4* pq    = (vfloat4*)(hbuf + (size_t)(T + 1) * BBH);  // T*8*NBS x16B
    int*   cnt     = (int*)(pq + (size_t)T * 8 * NBS);          // CNT_LINES*16
    int*   dct     = cnt + CNT_LINES * 16;           // 1 (never zeroed)

    hipFuncSetAttribute((const void*)kmain,
        hipFuncAttributeMaxDynamicSharedMemorySize,
        (int)SMEM_BYTES);

    kinit<<<16, 256, 0, stream>>>(hidden, hbuf, cnt, dct);
    kmain<<<NB, TPB, SMEM_BYTES, stream>>>(embedding, w_ih, w_hh, b_ih, b_hh,
                                           w_out, b_out, hbuf, pq,
                                           cnt, dct, out);
}